// Round 12
// baseline (291.417 us; speedup 1.0000x reference)
//
#include <hip/hip_runtime.h>
#include <stdint.h>
#include <stddef.h>

// Problem constants (B=2, S=2048, D=1024, I=2048, E=8)
#define T_TOK 4096
#define D_DIM 1024
#define I_DIM 2048
#define E_EXP 8

#define MAXT64  (T_TOK / 64 + E_EXP)    // 72
#define MAXT128 (T_TOK / 128 + E_EXP)   // 40
#define CAP (T_TOK + E_EXP * 128)       // 5120

// gemm1: 64x64x64, 4 waves, swizzled LDS (round-8 proven)
#define BT 64
#define NK1 (D_DIM / BT)    // 16
#define NC1 (I_DIM / BT)    // 32
#define G1_BLOCKS (MAXT64 * NC1)   // 2304
// gemm2: 128x64x64 (round-8 proven, swizzled)
#define BM2 128
#define BN2 64
#define BK2 64
#define NK2 (I_DIM / BK2)   // 32
#define NC2 (D_DIM / BN2)   // 16

typedef __attribute__((ext_vector_type(4))) float f32x4;
typedef __attribute__((ext_vector_type(4))) short s16x4;
typedef __attribute__((ext_vector_type(8))) short s16x8;
typedef __attribute__((ext_vector_type(2))) unsigned int u32x2;

__device__ __forceinline__ unsigned short f2bf(float f) {
    union { float f; unsigned u; } v; v.f = f;
    unsigned u = v.u;
    return (unsigned short)((u + 0x7fffu + ((u >> 16) & 1u)) >> 16);
}

__device__ __forceinline__ void gll16(const void* g, void* l) {
    __builtin_amdgcn_global_load_lds(
        (const __attribute__((address_space(1))) void*)g,
        (__attribute__((address_space(3))) void*)l, 16, 0, 0);
}

// ---------------------------------------------------------------- init
__global__ void k_init(int* idxl, int* counts, int* fill, float* sumP, float* lse2) {
    int tid = blockIdx.x * blockDim.x + threadIdx.x;
    for (int i = tid; i < CAP; i += blockDim.x * gridDim.x) idxl[i] = -1;
    if (blockIdx.x == 0 && threadIdx.x < E_EXP) {
        counts[threadIdx.x] = 0;
        fill[threadIdx.x] = 0;
        sumP[threadIdx.x] = 0.f;
    }
    if (blockIdx.x == 0 && threadIdx.x == 0) lse2[0] = 0.f;
}

// ---------------------------------------------------------------- router body (device): 4 tokens/wave, 256 blocks
// per-token code identical to round-8; only the token count per wave changed.
__device__ void router_block(
    const float* __restrict__ x, const float* __restrict__ gw,
    const float* __restrict__ pb, const float* __restrict__ tf,
    unsigned short* __restrict__ xb, int* __restrict__ selected,
    float* __restrict__ rw, int* __restrict__ counts,
    float* __restrict__ sumP, float* __restrict__ lse2)
{
    int gwave = (blockIdx.x * 256 + threadIdx.x) >> 6;   // 0..1023
    int lane = threadIdx.x & 63;

    float aP[E_EXP];
    int aC[E_EXP];
    float aZ = 0.f;
#pragma unroll
    for (int e = 0; e < E_EXP; e++) { aP[e] = 0.f; aC[e] = 0; }

    float tcl[E_EXP], pbv[E_EXP];
#pragma unroll
    for (int e = 0; e < E_EXP; e++) {
        tcl[e] = fminf(fmaxf(tf[e], 0.1f), 10.f);
        pbv[e] = pb[e];
    }

    for (int ti = 0; ti < 4; ++ti) {
        int t = gwave * 4 + ti;
        const float* xr = x + (size_t)t * D_DIM;
        float s[E_EXP];
#pragma unroll
        for (int e = 0; e < E_EXP; e++) s[e] = 0.f;

#pragma unroll
        for (int j = 0; j < 4; j++) {
            int d0 = j * 256 + lane * 4;
            f32x4 xv = *(const f32x4*)(xr + d0);
            s16x4 xs;
#pragma unroll
            for (int i = 0; i < 4; i++) xs[i] = (short)f2bf(xv[i]);
            *(s16x4*)(xb + (size_t)t * D_DIM + d0) = xs;
#pragma unroll
            for (int i = 0; i < 4; i++) {
                const float* gr = gw + (size_t)(d0 + i) * E_EXP;
                f32x4 g0 = *(const f32x4*)(gr);
                f32x4 g1 = *(const f32x4*)(gr + 4);
                float xi = xv[i];
                s[0] += xi * g0[0]; s[1] += xi * g0[1];
                s[2] += xi * g0[2]; s[3] += xi * g0[3];
                s[4] += xi * g1[0]; s[5] += xi * g1[1];
                s[6] += xi * g1[2]; s[7] += xi * g1[3];
            }
        }
#pragma unroll
        for (int m = 1; m < 64; m <<= 1) {
#pragma unroll
            for (int e = 0; e < E_EXP; e++) s[e] += __shfl_xor(s[e], m, 64);
        }
        float lg[E_EXP];
        float mx = -3.4e38f;
#pragma unroll
        for (int e = 0; e < E_EXP; e++) {
            lg[e] = (s[e] + pbv[e]) / tcl[e];
            mx = fmaxf(mx, lg[e]);
        }
        float p[E_EXP];
        float den = 0.f;
#pragma unroll
        for (int e = 0; e < E_EXP; e++) { p[e] = expf(lg[e] - mx); den += p[e]; }
        int sel = 0;
        float best = lg[0];
#pragma unroll
        for (int e = 1; e < E_EXP; e++) if (lg[e] > best) { best = lg[e]; sel = e; }
        float inv = 1.f / den;
        if (lane == 0) {
            selected[t] = sel;
            rw[t] = p[sel] * inv;
#pragma unroll
            for (int e = 0; e < E_EXP; e++) aP[e] += p[e] * inv;
            aC[sel] += 1;
            float lse = mx + logf(den);
            aZ += lse * lse;
        }
    }
    if (lane == 0) {
#pragma unroll
        for (int e = 0; e < E_EXP; e++) {
            atomicAdd(&sumP[e], aP[e]);
            if (aC[e]) atomicAdd(&counts[e], aC[e]);
        }
        atomicAdd(lse2, aZ);
    }
}

// ---------------------------------------------------------------- conv tile: fp32 [R][C] 128x128 tile -> bf16 [C][R] (round-8 proven, byte-identical)
__device__ void conv_tile(const float* __restrict__ src, unsigned short* __restrict__ dst,
                          int R, int C, int rt, int ct, unsigned short* tb)
{
    int r0 = rt * 128, c0 = ct * 128;
    int tid = threadIdx.x;
    int rr = tid >> 5;               // 0..7
    int cc = (tid & 31) * 4;         // 0..124

#pragma unroll
    for (int p = 0; p < 16; ++p) {
        int r = p * 8 + rr;
        f32x4 v = *(const f32x4*)(src + (size_t)(r0 + r) * C + c0 + cc);
        s16x4 w;
#pragma unroll
        for (int i = 0; i < 4; ++i) w[i] = (short)f2bf(v[i]);
        *(s16x4*)(tb + r * 130 + cc) = w;
    }
    __syncthreads();

    int rb = (tid & 15) * 4;         // 0..60
    int cp = (tid >> 4) * 2;         // 0..30 (even)
#pragma unroll
    for (int p = 0; p < 8; ++p) {
        int rh = (p & 1) * 64;
        int c = (p >> 1) * 32 + cp;  // even
        int rbase = rh + rb;
        unsigned int a0 = *(const unsigned int*)(tb + (rbase + 0) * 130 + c);
        unsigned int a1 = *(const unsigned int*)(tb + (rbase + 1) * 130 + c);
        unsigned int a2 = *(const unsigned int*)(tb + (rbase + 2) * 130 + c);
        unsigned int a3 = *(const unsigned int*)(tb + (rbase + 3) * 130 + c);
        u32x2 lo, hi;
        lo[0] = (a0 & 0xffffu) | (a1 << 16);
        lo[1] = (a2 & 0xffffu) | (a3 << 16);
        hi[0] = (a0 >> 16) | (a1 & 0xffff0000u);
        hi[1] = (a2 >> 16) | (a3 & 0xffff0000u);
        *(u32x2*)(dst + (size_t)(c0 + c) * R + r0 + rbase) = lo;
        *(u32x2*)(dst + (size_t)(c0 + c + 1) * R + r0 + rbase) = hi;
    }
}

// ---------------------------------------------------------------- fused1: router (blocks 0..255) + convert wg/wu (blocks 256..2303)
__global__ __launch_bounds__(256) void k_fused1(
    const float* __restrict__ x, const float* __restrict__ gw,
    const float* __restrict__ pb, const float* __restrict__ tf,
    unsigned short* __restrict__ xb, int* __restrict__ selected,
    float* __restrict__ rw, int* __restrict__ counts,
    float* __restrict__ sumP, float* __restrict__ lse2,
    const float* __restrict__ wg, const float* __restrict__ wu,
    unsigned short* __restrict__ wgT, unsigned short* __restrict__ wuT)
{
    __shared__ unsigned short tb[128 * 130];
    int bid = blockIdx.x;
    if (bid < 256) {
        router_block(x, gw, pb, tf, xb, selected, rw, counts, sumP, lse2);
        return;
    }
    int b = bid - 256;
    if (b < 1024) {
        int e = b >> 7, t = b & 127;
        conv_tile(wg + (size_t)e * D_DIM * I_DIM, wgT + (size_t)e * D_DIM * I_DIM,
                  D_DIM, I_DIM, t >> 4, t & 15, tb);
    } else {
        b -= 1024;
        int e = b >> 7, t = b & 127;
        conv_tile(wu + (size_t)e * D_DIM * I_DIM, wuT + (size_t)e * D_DIM * I_DIM,
                  D_DIM, I_DIM, t >> 4, t & 15, tb);
    }
}

// ---------------------------------------------------------------- setup (both tile tables)
__global__ void k_setup(const int* counts, int* segst,
                        int* t128e, int* t128b, int* t64e, int* t64b) {
    if (threadIdx.x == 0 && blockIdx.x == 0) {
        int off = 0, a = 0, b = 0;
        for (int e = 0; e < E_EXP; e++) {
            segst[e] = off;
            int n = counts[e];
            int n128 = (n + 127) >> 7;
            int n64 = (n + 63) >> 6;
            for (int i = 0; i < n128; i++) { t128e[a] = e; t128b[a] = off + i * 128; a++; }
            for (int i = 0; i < n64; i++)  { t64e[b] = e;  t64b[b] = off + i * 64;  b++; }
            off += n128 * 128;
        }
        for (; a < MAXT128; ++a) { t128e[a] = -1; t128b[a] = 0; }
        for (; b < MAXT64; ++b)  { t64e[b] = -1;  t64b[b] = 0; }
    }
}

// ---------------------------------------------------------------- scatter
__global__ void k_scatter(const int* selected, const int* segst, int* fill, int* idxl) {
    int t = blockIdx.x * 256 + threadIdx.x;
    if (t < T_TOK) {
        int e = selected[t];
        int p = atomicAdd(&fill[e], 1);
        idxl[segst[e] + p] = t;
    }
}

// ---------------------------------------------------------------- fused2: gemm1 (64x64x64, swizzled) + conv w_down interleaved  [round-8 proven]
__global__ __launch_bounds__(256) void k_fused2(
    const unsigned short* __restrict__ xb,
    const unsigned short* __restrict__ wgT,   // [E][I][D]; wuT at +E*I*D
    const int* __restrict__ idxl,
    const int* __restrict__ t64e, const int* __restrict__ t64b,
    unsigned short* __restrict__ H,
    const float* __restrict__ wd, unsigned short* __restrict__ wdT)
{
    __shared__ union {
        struct {
            unsigned short As[2][BT * BT];   // 2 x 8 KiB
            unsigned short Bg[2][BT * BT];
            unsigned short Bu[2][BT * BT];
        } g;
        unsigned short tb[128 * 130];
    } sm;

    int bid = blockIdx.x;
    int gid;
    if (bid < 2048) {
        if (bid & 1) {
            int b = bid >> 1;                  // conv w_down tile
            int e = b >> 7, t = b & 127;
            conv_tile(wd + (size_t)e * I_DIM * D_DIM, wdT + (size_t)e * I_DIM * D_DIM,
                      I_DIM, D_DIM, t >> 3, t & 7, sm.tb);
            return;
        }
        gid = bid >> 1;
    } else {
        gid = 1024 + (bid - 2048);
    }

    int rt = gid >> 5;          // NC1 = 32
    int ct = gid & 31;
    int e = t64e[rt];
    if (e < 0) return;
    int base = t64b[rt];

    int tid = threadIdx.x;
    int l = tid & 63;
    int w = tid >> 6;
    int rsub = l >> 3;                      // 0..7
    int csw = ((l & 7) ^ rsub) * 8;         // inverse-swizzled source chunk (elems)

    int tk0 = idxl[base + w * 16 + rsub];     tk0 = tk0 < 0 ? 0 : tk0;
    int tk1 = idxl[base + w * 16 + 8 + rsub]; tk1 = tk1 < 0 ? 0 : tk1;
    const unsigned short* gA0 = xb + (size_t)tk0 * D_DIM + csw;
    const unsigned short* gA1 = xb + (size_t)tk1 * D_DIM + csw;
    const size_t WOFF = (size_t)E_EXP * I_DIM * D_DIM;
    const unsigned short* gB0 = wgT + ((size_t)e * I_DIM + ct * 64 + w * 16 + rsub) * D_DIM + csw;
    const unsigned short* gB1 = gB0 + (size_t)8 * D_DIM;
    int aoff = w * 1024;                    // wave's 16 rows x 64

#define STAGE1(buf, ko) do { \
        gll16(gA0 + (ko), &sm.g.As[buf][aoff]); \
        gll16(gA1 + (ko), &sm.g.As[buf][aoff + 512]); \
        gll16(gB0 + (ko), &sm.g.Bg[buf][aoff]); \
        gll16(gB1 + (ko), &sm.g.Bg[buf][aoff + 512]); \
        gll16(gB0 + WOFF + (ko), &sm.g.Bu[buf][aoff]); \
        gll16(gB1 + WOFF + (ko), &sm.g.Bu[buf][aoff + 512]); \
    } while (0)

    int wm = (w >> 1) * 32;
    int wn = (w & 1) * 32;
    int lr = l & 15;
    int lxor = l & 7;

    f32x4 zero4 = {0.f, 0.f, 0.f, 0.f};
    f32x4 accG[2][2], accU[2][2];
#pragma unroll
    for (int i = 0; i < 2; i++)
#pragma unroll
        for (int j = 0; j < 2; j++) { accG[i][j] = zero4; accU[i][j] = zero4; }

    STAGE1(0, 0);
    __syncthreads();

    for (int kt = 0; kt < NK1; ++kt) {
        if (kt + 1 < NK1) STAGE1((kt + 1) & 1, (kt + 1) * BT);
        int b = kt & 1;
#pragma unroll
        for (int ks = 0; ks < 2; ++ks) {
            int kx = ((ks * 4 + (l >> 4)) ^ lxor) * 8;   // swizzled read chunk
            s16x8 af[2], bg[2], bu[2];
#pragma unroll
            for (int mi = 0; mi < 2; mi++)
                af[mi] = *(const s16x8*)(&sm.g.As[b][(wm + mi * 16 + lr) * 64 + kx]);
#pragma unroll
            for (int ni = 0; ni < 2; ni++) {
                bg[ni] = *(const s16x8*)(&sm.g.Bg[b][(wn + ni * 16 + lr) * 64 + kx]);
                bu[ni] = *(const s16x8*)(&sm.g.Bu[b][(wn + ni * 16 + lr) * 64 + kx]);
            }
#pragma unroll
            for (int mi = 0; mi < 2; mi++)
#pragma unroll
                for (int ni = 0; ni < 2; ni++) {
                    accG[mi][ni] = __builtin_amdgcn_mfma_f32_16x16x32_bf16(af[mi], bg[ni], accG[mi][ni], 0, 0, 0);
                    accU[mi][ni] = __builtin_amdgcn_mfma_f32_16x16x32_bf16(af[mi], bu[ni], accU[mi][ni], 0, 0, 0);
                }
        }
        __syncthreads();
    }
#undef STAGE1

    // epilogue: h = silu(g)*u -> bf16 H
#pragma unroll
    for (int mi = 0; mi < 2; mi++) {
#pragma unroll
        for (int r = 0; r < 4; r++) {
            int row = wm + mi * 16 + (l >> 4) * 4 + r;
            unsigned short* hr = H + (size_t)(base + row) * I_DIM + ct * 64 + wn + lr;
#pragma unroll
            for (int ni = 0; ni < 2; ni++) {
                float g = accG[mi][ni][r];
                float u = accU[mi][ni][r];
                float h = (g / (1.f + expf(-g))) * u;
                hr[ni * 16] = f2bf(h);
            }
        }
    }
}

// ---------------------------------------------------------------- gemm2: 128x64x64 + XOR swizzle (round-8 proven); out = (H Wd)*rw
__global__ __launch_bounds__(256) void k_gemm2(
    const unsigned short* __restrict__ H,
    const unsigned short* __restrict__ wdT,   // [E][D][I]
    const int* __restrict__ idxl, const float* __restrict__ rw,
    const int* __restrict__ t128e, const int* __restrict__ t128b,
    float* __restrict__ out)
{
    __shared__ unsigned short As2[2][BM2 * BK2];  // 2 x 16 KiB
    __shared__ unsigned short Bs2[2][BN2 * BK2];  // 2 x 8 KiB
    __shared__ int s_tok[BM2];
    __shared__ float s_rw[BM2];

    int bid = blockIdx.x;
    int rt = bid >> 4;
    int ct = bid & 15;
    int e = t128e[rt];
    if (e < 0) return;
    int base = t128b[rt];

    int tid = threadIdx.x;
    int lane = tid & 63;
    int wid = tid >> 6;

    if (tid < BM2) {
        int tk = idxl[base + tid];
        s_tok[tid] = tk;
        s_rw[tid] = (tk >= 0) ? rw[tk] : 0.f;
    }

    int rsub = lane >> 3;                         // 0..7
    int csw = ((lane & 7) ^ rsub) * 8;            // inverse-swizzled source chunk (elems)
    int ar = wid * 32 + rsub;
    const unsigned short* gA = H + (size_t)(base + ar) * I_DIM + csw;
    int br = wid * 16 + rsub;
    const unsigned short* gB = wdT + ((size_t)e * D_DIM + (size_t)ct * BN2 + br) * I_DIM + csw;

    int aoff = wid * 32 * BK2;
    int boff = wid * 16 * BK2;

#define STAGE2(buf, ko) do { \
        gll16(gA + (ko),                      &As2[buf][aoff]); \
        gll16(gA + (size_t)8  * I_DIM + (ko), &As2[buf][aoff + 8 * BK2]); \
        gll16(gA + (size_t)16 * I_DIM + (ko), &As2[buf][aoff + 16 * BK2]); \
        gll16(gA + (size_t)24 * I_DIM + (ko), &As2[buf][aoff + 24 * BK2]); \
        gll16(gB + (ko),                      &Bs2[buf][boff]); \
        gll16(gB + (size_t)8 * I_DIM + (ko),  &Bs2[buf][boff + 8 * BK2]); \
    } while (0)

    int wm = (wid >> 1) * 64;
    int wn = (wid & 1) * 32;
    int lr = lane & 15;
    int lxor = lane & 7;

    f32x4 zero4 = {0.f, 0.f, 0.f, 0.f};
    f32x4 acc[4][2];
#pragma unroll
    for (int i = 0; i < 4; i++)
#pragma unroll
        for (int j = 0; j < 2; j++) acc[i][j] = zero4;

    STAGE2(0, 0);
    __syncthreads();

    for (int kt = 0; kt < NK2; ++kt) {
        if (kt + 1 < NK2) STAGE2((kt + 1) & 1, (kt + 1) * BK2);
        int b = kt & 1;
#pragma unroll
        for (int ks = 0; ks < 2; ++ks) {
            int kx = ((ks * 4 + (lane >> 4)) ^ lxor) * 8;   // swizzled read chunk
            s16x8 af[4], bf[2];
#pragma unroll
            for (int mi = 0; mi < 4; mi++)
                af[mi] = *(const s16x8*)&As2[b][(wm + mi * 16 + lr) * BK2 + kx];
#pragma unroll
            for (int ni = 0; ni < 2; ni++)
                bf[ni] = *(const s16x8*)&Bs2[b][(wn + ni * 16 + lr) * BK2 + kx];
#pragma unroll
            for (int mi = 0; mi < 4; mi++)
#pragma unroll
                for (int ni = 0; ni < 2; ni++)
                    acc[mi][ni] = __builtin_amdgcn_mfma_f32_16x16x32_bf16(af[mi], bf[ni], acc[mi][ni], 0, 0, 0);
        }
        __syncthreads();
    }
#undef STAGE2

#pragma unroll
    for (int mi = 0; mi < 4; mi++) {
#pragma unroll
        for (int r = 0; r < 4; r++) {
            int row = wm + mi * 16 + (lane >> 4) * 4 + r;
            int tk = s_tok[row];
            if (tk >= 0) {
                float scale = s_rw[row];
                float* orow = out + (size_t)tk * D_DIM + (size_t)ct * BN2 + wn + lr;
#pragma unroll
                for (int ni = 0; ni < 2; ni++)
                    orow[ni * 16] = acc[mi][ni][r] * scale;
            }
        }
    }
}

// ---------------------------------------------------------------- aux loss
__global__ void k_aux(const int* counts, const float* sumP, const float* lse2, float* out) {
    if (threadIdx.x == 0 && blockIdx.x == 0) {
        float lb = 0.f;
        for (int e = 0; e < E_EXP; e++) {
            float f = (float)counts[e] / (float)T_TOK;
            float P = sumP[e] / (float)T_TOK;
            lb += f * P;
        }
        float aux = 0.01f * ((float)E_EXP * lb) + 0.001f * (lse2[0] / (float)T_TOK);
        out[(size_t)T_TOK * D_DIM] = aux;
    }
}

// ---------------------------------------------------------------- launch
extern "C" void kernel_launch(void* const* d_in, const int* in_sizes, int n_in,
                              void* d_out, int out_size, void* d_ws, size_t ws_size,
                              hipStream_t stream)
{
    const float* x      = (const float*)d_in[0];
    const float* gw     = (const float*)d_in[1];
    const float* w_gate = (const float*)d_in[2];
    const float* w_up   = (const float*)d_in[3];
    const float* w_down = (const float*)d_in[4];
    const float* pb     = (const float*)d_in[5];
    const float* tf     = (const float*)d_in[6];
    float* out = (float*)d_out;

    char* ws = (char*)d_ws;
    int*   selected = (int*)ws;
    float* rwp      = (float*)(selected + T_TOK);
    int*   idxl     = (int*)(rwp + T_TOK);
    int*   counts   = idxl + CAP;
    int*   fill     = counts + E_EXP;
    int*   segst    = fill + E_EXP;
    int*   t128e    = segst + E_EXP;
    int*   t128b    = t128e + MAXT128;
    int*   t64e     = t128b + MAXT128;
    int*   t64b     = t64e + MAXT64;
    float* sumP     = (float*)(t64b + MAXT64);
    float* lse2     = sumP + E_EXP;

    const size_t XB_OFF  = 65536;
    const size_t H_OFF   = XB_OFF + (size_t)T_TOK * D_DIM * 2;
    const size_t WGT_OFF = H_OFF + (size_t)CAP * I_DIM * 2;
    const size_t WUT_OFF = WGT_OFF + (size_t)E_EXP * I_DIM * D_DIM * 2;
    const size_t WDT_OFF = WUT_OFF + (size_t)E_EXP * I_DIM * D_DIM * 2;

    unsigned short* xb  = (unsigned short*)(ws + XB_OFF);
    unsigned short* H   = (unsigned short*)(ws + H_OFF);
    unsigned short* wgT = (unsigned short*)(ws + WGT_OFF);
    unsigned short* wuT = (unsigned short*)(ws + WUT_OFF);
    unsigned short* wdT = (unsigned short*)(ws + WDT_OFF);

    k_init<<<dim3(8), dim3(256), 0, stream>>>(idxl, counts, fill, sumP, lse2);
    // router (256 blocks, 4 tok/wave) + convert wg/wu (2048 blocks) fused
    k_fused1<<<dim3(256 + 2048), dim3(256), 0, stream>>>(
        x, gw, pb, tf, xb, selected, rwp, counts, sumP, lse2,
        w_gate, w_up, wgT, wuT);
    k_setup<<<dim3(1), dim3(64), 0, stream>>>(counts, segst, t128e, t128b, t64e, t64b);
    k_scatter<<<dim3(16), dim3(256), 0, stream>>>(selected, segst, fill, idxl);
    // gemm1 (2304 blocks) + convert w_down (1024 blocks) fused, interleaved
    k_fused2<<<dim3(G1_BLOCKS + 1024), dim3(256), 0, stream>>>(
        xb, wgT, idxl, t64e, t64b, H, w_down, wdT);
    k_gemm2<<<dim3(MAXT128 * NC2), dim3(256), 0, stream>>>(H, wdT, idxl, rwp, t128e, t128b, out);
    k_aux<<<dim3(1), dim3(64), 0, stream>>>(counts, sumP, lse2, out);
}

// Round 13
// 208.773 us; speedup vs baseline: 1.3959x; 1.3959x over previous
//
#include <hip/hip_runtime.h>
#include <stdint.h>
#include <stddef.h>

// Problem constants (B=2, S=2048, D=1024, I=2048, E=8)
#define T_TOK 4096
#define D_DIM 1024
#define I_DIM 2048
#define E_EXP 8

#define MAXT64  (T_TOK / 64 + E_EXP)    // 72
#define MAXT128 (T_TOK / 128 + E_EXP)   // 40
#define CAP (T_TOK + E_EXP * 128)       // 5120

// gemm1: 64x64x64, 4 waves, swizzled LDS (round-8 proven)
#define BT 64
#define NK1 (D_DIM / BT)    // 16
#define NC1 (I_DIM / BT)    // 32
#define G1_BLOCKS (MAXT64 * NC1)   // 2304
// gemm2: 128x64x64 (round-8 proven, swizzled)
#define BM2 128
#define BN2 64
#define BK2 64
#define NK2 (I_DIM / BK2)   // 32
#define NC2 (D_DIM / BN2)   // 16

typedef __attribute__((ext_vector_type(4))) float f32x4;
typedef __attribute__((ext_vector_type(4))) short s16x4;
typedef __attribute__((ext_vector_type(8))) short s16x8;
typedef __attribute__((ext_vector_type(2))) unsigned int u32x2;

__device__ __forceinline__ unsigned short f2bf(float f) {
    union { float f; unsigned u; } v; v.f = f;
    unsigned u = v.u;
    return (unsigned short)((u + 0x7fffu + ((u >> 16) & 1u)) >> 16);
}

__device__ __forceinline__ void gll16(const void* g, void* l) {
    __builtin_amdgcn_global_load_lds(
        (const __attribute__((address_space(1))) void*)g,
        (__attribute__((address_space(3))) void*)l, 16, 0, 0);
}

// ---------------------------------------------------------------- init
__global__ void k_init(int* idxl, int* counts, int* fill, float* sumP, float* lse2) {
    int tid = blockIdx.x * blockDim.x + threadIdx.x;
    for (int i = tid; i < CAP; i += blockDim.x * gridDim.x) idxl[i] = -1;
    if (blockIdx.x == 0 && threadIdx.x < E_EXP) {
        counts[threadIdx.x] = 0;
        fill[threadIdx.x] = 0;
        sumP[threadIdx.x] = 0.f;
    }
    if (blockIdx.x == 0 && threadIdx.x == 0) lse2[0] = 0.f;
}

// ---------------------------------------------------------------- router body (device): 16 tokens/wave, 64 blocks (round-8 proven token loop)
// NEW (G12): per-block LDS reduction of aP/aC/aZ; ONE set of global atomics per block.
__device__ void router_block(
    const float* __restrict__ x, const float* __restrict__ gw,
    const float* __restrict__ pb, const float* __restrict__ tf,
    unsigned short* __restrict__ xb, int* __restrict__ selected,
    float* __restrict__ rw, int* __restrict__ counts,
    float* __restrict__ sumP, float* __restrict__ lse2,
    float* redP, int* redC, float* redZ)      // LDS: [4][8], [4][8], [4]
{
    int gwave = (blockIdx.x * 256 + threadIdx.x) >> 6;
    int lane = threadIdx.x & 63;
    int wv = threadIdx.x >> 6;

    float aP[E_EXP];
    int aC[E_EXP];
    float aZ = 0.f;
#pragma unroll
    for (int e = 0; e < E_EXP; e++) { aP[e] = 0.f; aC[e] = 0; }

    float tcl[E_EXP], pbv[E_EXP];
#pragma unroll
    for (int e = 0; e < E_EXP; e++) {
        tcl[e] = fminf(fmaxf(tf[e], 0.1f), 10.f);
        pbv[e] = pb[e];
    }

    for (int ti = 0; ti < 16; ++ti) {
        int t = gwave * 16 + ti;
        const float* xr = x + (size_t)t * D_DIM;
        float s[E_EXP];
#pragma unroll
        for (int e = 0; e < E_EXP; e++) s[e] = 0.f;

#pragma unroll
        for (int j = 0; j < 4; j++) {
            int d0 = j * 256 + lane * 4;
            f32x4 xv = *(const f32x4*)(xr + d0);
            s16x4 xs;
#pragma unroll
            for (int i = 0; i < 4; i++) xs[i] = (short)f2bf(xv[i]);
            *(s16x4*)(xb + (size_t)t * D_DIM + d0) = xs;
#pragma unroll
            for (int i = 0; i < 4; i++) {
                const float* gr = gw + (size_t)(d0 + i) * E_EXP;
                f32x4 g0 = *(const f32x4*)(gr);
                f32x4 g1 = *(const f32x4*)(gr + 4);
                float xi = xv[i];
                s[0] += xi * g0[0]; s[1] += xi * g0[1];
                s[2] += xi * g0[2]; s[3] += xi * g0[3];
                s[4] += xi * g1[0]; s[5] += xi * g1[1];
                s[6] += xi * g1[2]; s[7] += xi * g1[3];
            }
        }
#pragma unroll
        for (int m = 1; m < 64; m <<= 1) {
#pragma unroll
            for (int e = 0; e < E_EXP; e++) s[e] += __shfl_xor(s[e], m, 64);
        }
        float lg[E_EXP];
        float mx = -3.4e38f;
#pragma unroll
        for (int e = 0; e < E_EXP; e++) {
            lg[e] = (s[e] + pbv[e]) / tcl[e];
            mx = fmaxf(mx, lg[e]);
        }
        float p[E_EXP];
        float den = 0.f;
#pragma unroll
        for (int e = 0; e < E_EXP; e++) { p[e] = expf(lg[e] - mx); den += p[e]; }
        int sel = 0;
        float best = lg[0];
#pragma unroll
        for (int e = 1; e < E_EXP; e++) if (lg[e] > best) { best = lg[e]; sel = e; }
        float inv = 1.f / den;
        if (lane == 0) {
            selected[t] = sel;
            rw[t] = p[sel] * inv;
#pragma unroll
            for (int e = 0; e < E_EXP; e++) aP[e] += p[e] * inv;
            aC[sel] += 1;
            float lse = mx + logf(den);
            aZ += lse * lse;
        }
    }
    // per-block reduction (G12): 4 waves -> LDS -> one atomic set per block
    if (lane == 0) {
#pragma unroll
        for (int e = 0; e < E_EXP; e++) {
            redP[wv * E_EXP + e] = aP[e];
            redC[wv * E_EXP + e] = aC[e];
        }
        redZ[wv] = aZ;
    }
    __syncthreads();
    if (threadIdx.x == 0) {
#pragma unroll
        for (int e = 0; e < E_EXP; e++) {
            float p = redP[e] + redP[8 + e] + redP[16 + e] + redP[24 + e];
            int c = redC[e] + redC[8 + e] + redC[16 + e] + redC[24 + e];
            atomicAdd(&sumP[e], p);
            if (c) atomicAdd(&counts[e], c);
        }
        atomicAdd(lse2, redZ[0] + redZ[1] + redZ[2] + redZ[3]);
    }
}

// ---------------------------------------------------------------- conv tile: fp32 [R][C] 128x128 tile -> bf16 [C][R] (round-8 proven, byte-identical)
__device__ void conv_tile(const float* __restrict__ src, unsigned short* __restrict__ dst,
                          int R, int C, int rt, int ct, unsigned short* tb)
{
    int r0 = rt * 128, c0 = ct * 128;
    int tid = threadIdx.x;
    int rr = tid >> 5;               // 0..7
    int cc = (tid & 31) * 4;         // 0..124

#pragma unroll
    for (int p = 0; p < 16; ++p) {
        int r = p * 8 + rr;
        f32x4 v = *(const f32x4*)(src + (size_t)(r0 + r) * C + c0 + cc);
        s16x4 w;
#pragma unroll
        for (int i = 0; i < 4; ++i) w[i] = (short)f2bf(v[i]);
        *(s16x4*)(tb + r * 130 + cc) = w;
    }
    __syncthreads();

    int rb = (tid & 15) * 4;         // 0..60
    int cp = (tid >> 4) * 2;         // 0..30 (even)
#pragma unroll
    for (int p = 0; p < 8; ++p) {
        int rh = (p & 1) * 64;
        int c = (p >> 1) * 32 + cp;  // even
        int rbase = rh + rb;
        unsigned int a0 = *(const unsigned int*)(tb + (rbase + 0) * 130 + c);
        unsigned int a1 = *(const unsigned int*)(tb + (rbase + 1) * 130 + c);
        unsigned int a2 = *(const unsigned int*)(tb + (rbase + 2) * 130 + c);
        unsigned int a3 = *(const unsigned int*)(tb + (rbase + 3) * 130 + c);
        u32x2 lo, hi;
        lo[0] = (a0 & 0xffffu) | (a1 << 16);
        lo[1] = (a2 & 0xffffu) | (a3 << 16);
        hi[0] = (a0 >> 16) | (a1 & 0xffff0000u);
        hi[1] = (a2 >> 16) | (a3 & 0xffff0000u);
        *(u32x2*)(dst + (size_t)(c0 + c) * R + r0 + rbase) = lo;
        *(u32x2*)(dst + (size_t)(c0 + c + 1) * R + r0 + rbase) = hi;
    }
}

// ---------------------------------------------------------------- fused1: router (blocks 0..63) + convert wg/wu (blocks 64..2111)  [round-8 layout]
__global__ __launch_bounds__(256) void k_fused1(
    const float* __restrict__ x, const float* __restrict__ gw,
    const float* __restrict__ pb, const float* __restrict__ tf,
    unsigned short* __restrict__ xb, int* __restrict__ selected,
    float* __restrict__ rw, int* __restrict__ counts,
    float* __restrict__ sumP, float* __restrict__ lse2,
    const float* __restrict__ wg, const float* __restrict__ wu,
    unsigned short* __restrict__ wgT, unsigned short* __restrict__ wuT)
{
    __shared__ union {
        unsigned short tb[128 * 130];
        struct { float P[32]; int C[32]; float Z[4]; } red;
    } sm;
    int bid = blockIdx.x;
    if (bid < 64) {
        router_block(x, gw, pb, tf, xb, selected, rw, counts, sumP, lse2,
                     sm.red.P, sm.red.C, sm.red.Z);
        return;
    }
    int b = bid - 64;
    if (b < 1024) {
        int e = b >> 7, t = b & 127;
        conv_tile(wg + (size_t)e * D_DIM * I_DIM, wgT + (size_t)e * D_DIM * I_DIM,
                  D_DIM, I_DIM, t >> 4, t & 15, sm.tb);
    } else {
        b -= 1024;
        int e = b >> 7, t = b & 127;
        conv_tile(wu + (size_t)e * D_DIM * I_DIM, wuT + (size_t)e * D_DIM * I_DIM,
                  D_DIM, I_DIM, t >> 4, t & 15, sm.tb);
    }
}

// ---------------------------------------------------------------- setup (both tile tables)
__global__ void k_setup(const int* counts, int* segst,
                        int* t128e, int* t128b, int* t64e, int* t64b) {
    if (threadIdx.x == 0 && blockIdx.x == 0) {
        int off = 0, a = 0, b = 0;
        for (int e = 0; e < E_EXP; e++) {
            segst[e] = off;
            int n = counts[e];
            int n128 = (n + 127) >> 7;
            int n64 = (n + 63) >> 6;
            for (int i = 0; i < n128; i++) { t128e[a] = e; t128b[a] = off + i * 128; a++; }
            for (int i = 0; i < n64; i++)  { t64e[b] = e;  t64b[b] = off + i * 64;  b++; }
            off += n128 * 128;
        }
        for (; a < MAXT128; ++a) { t128e[a] = -1; t128b[a] = 0; }
        for (; b < MAXT64; ++b)  { t64e[b] = -1;  t64b[b] = 0; }
    }
}

// ---------------------------------------------------------------- scatter
__global__ void k_scatter(const int* selected, const int* segst, int* fill, int* idxl) {
    int t = blockIdx.x * 256 + threadIdx.x;
    if (t < T_TOK) {
        int e = selected[t];
        int p = atomicAdd(&fill[e], 1);
        idxl[segst[e] + p] = t;
    }
}

// ---------------------------------------------------------------- fused2: gemm1 (64x64x64, swizzled) + conv w_down interleaved  [round-8 proven]
__global__ __launch_bounds__(256) void k_fused2(
    const unsigned short* __restrict__ xb,
    const unsigned short* __restrict__ wgT,   // [E][I][D]; wuT at +E*I*D
    const int* __restrict__ idxl,
    const int* __restrict__ t64e, const int* __restrict__ t64b,
    unsigned short* __restrict__ H,
    const float* __restrict__ wd, unsigned short* __restrict__ wdT)
{
    __shared__ union {
        struct {
            unsigned short As[2][BT * BT];   // 2 x 8 KiB
            unsigned short Bg[2][BT * BT];
            unsigned short Bu[2][BT * BT];
        } g;
        unsigned short tb[128 * 130];
    } sm;

    int bid = blockIdx.x;
    int gid;
    if (bid < 2048) {
        if (bid & 1) {
            int b = bid >> 1;                  // conv w_down tile
            int e = b >> 7, t = b & 127;
            conv_tile(wd + (size_t)e * I_DIM * D_DIM, wdT + (size_t)e * I_DIM * D_DIM,
                      I_DIM, D_DIM, t >> 3, t & 7, sm.tb);
            return;
        }
        gid = bid >> 1;
    } else {
        gid = 1024 + (bid - 2048);
    }

    int rt = gid >> 5;          // NC1 = 32
    int ct = gid & 31;
    int e = t64e[rt];
    if (e < 0) return;
    int base = t64b[rt];

    int tid = threadIdx.x;
    int l = tid & 63;
    int w = tid >> 6;
    int rsub = l >> 3;                      // 0..7
    int csw = ((l & 7) ^ rsub) * 8;         // inverse-swizzled source chunk (elems)

    int tk0 = idxl[base + w * 16 + rsub];     tk0 = tk0 < 0 ? 0 : tk0;
    int tk1 = idxl[base + w * 16 + 8 + rsub]; tk1 = tk1 < 0 ? 0 : tk1;
    const unsigned short* gA0 = xb + (size_t)tk0 * D_DIM + csw;
    const unsigned short* gA1 = xb + (size_t)tk1 * D_DIM + csw;
    const size_t WOFF = (size_t)E_EXP * I_DIM * D_DIM;
    const unsigned short* gB0 = wgT + ((size_t)e * I_DIM + ct * 64 + w * 16 + rsub) * D_DIM + csw;
    const unsigned short* gB1 = gB0 + (size_t)8 * D_DIM;
    int aoff = w * 1024;                    // wave's 16 rows x 64

#define STAGE1(buf, ko) do { \
        gll16(gA0 + (ko), &sm.g.As[buf][aoff]); \
        gll16(gA1 + (ko), &sm.g.As[buf][aoff + 512]); \
        gll16(gB0 + (ko), &sm.g.Bg[buf][aoff]); \
        gll16(gB1 + (ko), &sm.g.Bg[buf][aoff + 512]); \
        gll16(gB0 + WOFF + (ko), &sm.g.Bu[buf][aoff]); \
        gll16(gB1 + WOFF + (ko), &sm.g.Bu[buf][aoff + 512]); \
    } while (0)

    int wm = (w >> 1) * 32;
    int wn = (w & 1) * 32;
    int lr = l & 15;
    int lxor = l & 7;

    f32x4 zero4 = {0.f, 0.f, 0.f, 0.f};
    f32x4 accG[2][2], accU[2][2];
#pragma unroll
    for (int i = 0; i < 2; i++)
#pragma unroll
        for (int j = 0; j < 2; j++) { accG[i][j] = zero4; accU[i][j] = zero4; }

    STAGE1(0, 0);
    __syncthreads();

    for (int kt = 0; kt < NK1; ++kt) {
        if (kt + 1 < NK1) STAGE1((kt + 1) & 1, (kt + 1) * BT);
        int b = kt & 1;
#pragma unroll
        for (int ks = 0; ks < 2; ++ks) {
            int kx = ((ks * 4 + (l >> 4)) ^ lxor) * 8;   // swizzled read chunk
            s16x8 af[2], bg[2], bu[2];
#pragma unroll
            for (int mi = 0; mi < 2; mi++)
                af[mi] = *(const s16x8*)(&sm.g.As[b][(wm + mi * 16 + lr) * 64 + kx]);
#pragma unroll
            for (int ni = 0; ni < 2; ni++) {
                bg[ni] = *(const s16x8*)(&sm.g.Bg[b][(wn + ni * 16 + lr) * 64 + kx]);
                bu[ni] = *(const s16x8*)(&sm.g.Bu[b][(wn + ni * 16 + lr) * 64 + kx]);
            }
#pragma unroll
            for (int mi = 0; mi < 2; mi++)
#pragma unroll
                for (int ni = 0; ni < 2; ni++) {
                    accG[mi][ni] = __builtin_amdgcn_mfma_f32_16x16x32_bf16(af[mi], bg[ni], accG[mi][ni], 0, 0, 0);
                    accU[mi][ni] = __builtin_amdgcn_mfma_f32_16x16x32_bf16(af[mi], bu[ni], accU[mi][ni], 0, 0, 0);
                }
        }
        __syncthreads();
    }
#undef STAGE1

    // epilogue: h = silu(g)*u -> bf16 H
#pragma unroll
    for (int mi = 0; mi < 2; mi++) {
#pragma unroll
        for (int r = 0; r < 4; r++) {
            int row = wm + mi * 16 + (l >> 4) * 4 + r;
            unsigned short* hr = H + (size_t)(base + row) * I_DIM + ct * 64 + wn + lr;
#pragma unroll
            for (int ni = 0; ni < 2; ni++) {
                float g = accG[mi][ni][r];
                float u = accU[mi][ni][r];
                float h = (g / (1.f + expf(-g))) * u;
                hr[ni * 16] = f2bf(h);
            }
        }
    }
}

// ---------------------------------------------------------------- gemm2: 128x64x64 + XOR swizzle (round-8 proven); out = (H Wd)*rw
__global__ __launch_bounds__(256) void k_gemm2(
    const unsigned short* __restrict__ H,
    const unsigned short* __restrict__ wdT,   // [E][D][I]
    const int* __restrict__ idxl, const float* __restrict__ rw,
    const int* __restrict__ t128e, const int* __restrict__ t128b,
    float* __restrict__ out)
{
    __shared__ unsigned short As2[2][BM2 * BK2];  // 2 x 16 KiB
    __shared__ unsigned short Bs2[2][BN2 * BK2];  // 2 x 8 KiB
    __shared__ int s_tok[BM2];
    __shared__ float s_rw[BM2];

    int bid = blockIdx.x;
    int rt = bid >> 4;
    int ct = bid & 15;
    int e = t128e[rt];
    if (e < 0) return;
    int base = t128b[rt];

    int tid = threadIdx.x;
    int lane = tid & 63;
    int wid = tid >> 6;

    if (tid < BM2) {
        int tk = idxl[base + tid];
        s_tok[tid] = tk;
        s_rw[tid] = (tk >= 0) ? rw[tk] : 0.f;
    }

    int rsub = lane >> 3;                         // 0..7
    int csw = ((lane & 7) ^ rsub) * 8;            // inverse-swizzled source chunk (elems)
    int ar = wid * 32 + rsub;
    const unsigned short* gA = H + (size_t)(base + ar) * I_DIM + csw;
    int br = wid * 16 + rsub;
    const unsigned short* gB = wdT + ((size_t)e * D_DIM + (size_t)ct * BN2 + br) * I_DIM + csw;

    int aoff = wid * 32 * BK2;
    int boff = wid * 16 * BK2;

#define STAGE2(buf, ko) do { \
        gll16(gA + (ko),                      &As2[buf][aoff]); \
        gll16(gA + (size_t)8  * I_DIM + (ko), &As2[buf][aoff + 8 * BK2]); \
        gll16(gA + (size_t)16 * I_DIM + (ko), &As2[buf][aoff + 16 * BK2]); \
        gll16(gA + (size_t)24 * I_DIM + (ko), &As2[buf][aoff + 24 * BK2]); \
        gll16(gB + (ko),                      &Bs2[buf][boff]); \
        gll16(gB + (size_t)8 * I_DIM + (ko),  &Bs2[buf][boff + 8 * BK2]); \
    } while (0)

    int wm = (wid >> 1) * 64;
    int wn = (wid & 1) * 32;
    int lr = lane & 15;
    int lxor = lane & 7;

    f32x4 zero4 = {0.f, 0.f, 0.f, 0.f};
    f32x4 acc[4][2];
#pragma unroll
    for (int i = 0; i < 4; i++)
#pragma unroll
        for (int j = 0; j < 2; j++) acc[i][j] = zero4;

    STAGE2(0, 0);
    __syncthreads();

    for (int kt = 0; kt < NK2; ++kt) {
        if (kt + 1 < NK2) STAGE2((kt + 1) & 1, (kt + 1) * BK2);
        int b = kt & 1;
#pragma unroll
        for (int ks = 0; ks < 2; ++ks) {
            int kx = ((ks * 4 + (lane >> 4)) ^ lxor) * 8;   // swizzled read chunk
            s16x8 af[4], bf[2];
#pragma unroll
            for (int mi = 0; mi < 4; mi++)
                af[mi] = *(const s16x8*)&As2[b][(wm + mi * 16 + lr) * BK2 + kx];
#pragma unroll
            for (int ni = 0; ni < 2; ni++)
                bf[ni] = *(const s16x8*)&Bs2[b][(wn + ni * 16 + lr) * BK2 + kx];
#pragma unroll
            for (int mi = 0; mi < 4; mi++)
#pragma unroll
                for (int ni = 0; ni < 2; ni++)
                    acc[mi][ni] = __builtin_amdgcn_mfma_f32_16x16x32_bf16(af[mi], bf[ni], acc[mi][ni], 0, 0, 0);
        }
        __syncthreads();
    }
#undef STAGE2

#pragma unroll
    for (int mi = 0; mi < 4; mi++) {
#pragma unroll
        for (int r = 0; r < 4; r++) {
            int row = wm + mi * 16 + (lane >> 4) * 4 + r;
            int tk = s_tok[row];
            if (tk >= 0) {
                float scale = s_rw[row];
                float* orow = out + (size_t)tk * D_DIM + (size_t)ct * BN2 + wn + lr;
#pragma unroll
                for (int ni = 0; ni < 2; ni++)
                    orow[ni * 16] = acc[mi][ni][r] * scale;
            }
        }
    }
}

// ---------------------------------------------------------------- aux loss
__global__ void k_aux(const int* counts, const float* sumP, const float* lse2, float* out) {
    if (threadIdx.x == 0 && blockIdx.x == 0) {
        float lb = 0.f;
        for (int e = 0; e < E_EXP; e++) {
            float f = (float)counts[e] / (float)T_TOK;
            float P = sumP[e] / (float)T_TOK;
            lb += f * P;
        }
        float aux = 0.01f * ((float)E_EXP * lb) + 0.001f * (lse2[0] / (float)T_TOK);
        out[(size_t)T_TOK * D_DIM] = aux;
    }
}

// ---------------------------------------------------------------- launch
extern "C" void kernel_launch(void* const* d_in, const int* in_sizes, int n_in,
                              void* d_out, int out_size, void* d_ws, size_t ws_size,
                              hipStream_t stream)
{
    const float* x      = (const float*)d_in[0];
    const float* gw     = (const float*)d_in[1];
    const float* w_gate = (const float*)d_in[2];
    const float* w_up   = (const float*)d_in[3];
    const float* w_down = (const float*)d_in[4];
    const float* pb     = (const float*)d_in[5];
    const float* tf     = (const float*)d_in[6];
    float* out = (float*)d_out;

    char* ws = (char*)d_ws;
    int*   selected = (int*)ws;
    float* rwp      = (float*)(selected + T_TOK);
    int*   idxl     = (int*)(rwp + T_TOK);
    int*   counts   = idxl + CAP;
    int*   fill     = counts + E_EXP;
    int*   segst    = fill + E_EXP;
    int*   t128e    = segst + E_EXP;
    int*   t128b    = t128e + MAXT128;
    int*   t64e     = t128b + MAXT128;
    int*   t64b     = t64e + MAXT64;
    float* sumP     = (float*)(t64b + MAXT64);
    float* lse2     = sumP + E_EXP;

    const size_t XB_OFF  = 65536;
    const size_t H_OFF   = XB_OFF + (size_t)T_TOK * D_DIM * 2;
    const size_t WGT_OFF = H_OFF + (size_t)CAP * I_DIM * 2;
    const size_t WUT_OFF = WGT_OFF + (size_t)E_EXP * I_DIM * D_DIM * 2;
    const size_t WDT_OFF = WUT_OFF + (size_t)E_EXP * I_DIM * D_DIM * 2;

    unsigned short* xb  = (unsigned short*)(ws + XB_OFF);
    unsigned short* H   = (unsigned short*)(ws + H_OFF);
    unsigned short* wgT = (unsigned short*)(ws + WGT_OFF);
    unsigned short* wuT = (unsigned short*)(ws + WUT_OFF);
    unsigned short* wdT = (unsigned short*)(ws + WDT_OFF);

    k_init<<<dim3(8), dim3(256), 0, stream>>>(idxl, counts, fill, sumP, lse2);
    // router (64 blocks) + convert wg/wu (2048 blocks) fused
    k_fused1<<<dim3(64 + 2048), dim3(256), 0, stream>>>(
        x, gw, pb, tf, xb, selected, rwp, counts, sumP, lse2,
        w_gate, w_up, wgT, wuT);
    k_setup<<<dim3(1), dim3(64), 0, stream>>>(counts, segst, t128e, t128b, t64e, t64b);
    k_scatter<<<dim3(16), dim3(256), 0, stream>>>(selected, segst, fill, idxl);
    // gemm1 (2304 blocks) + convert w_down (1024 blocks) fused, interleaved
    k_fused2<<<dim3(G1_BLOCKS + 1024), dim3(256), 0, stream>>>(
        xb, wgT, idxl, t64e, t64b, H, w_down, wdT);
    k_gemm2<<<dim3(MAXT128 * NC2), dim3(256), 0, stream>>>(H, wdT, idxl, rwp, t128e, t128b, out);
    k_aux<<<dim3(1), dim3(64), 0, stream>>>(counts, sumP, lse2, out);
}